// Round 6
// baseline (12545.661 us; speedup 1.0000x reference)
//
#include <hip/hip_runtime.h>
#include <hip/hip_cooperative_groups.h>
#include <cstdint>
#include <cstddef>

namespace cg = cooperative_groups;

#define HH 512
#define BB 64
#define TT 256
#define GG 2048   // 4*HH
#define NCLS 50257

typedef __attribute__((ext_vector_type(4))) float f32x4;
typedef __attribute__((ext_vector_type(8))) short bf16x8;

__device__ __forceinline__ unsigned short bf16_rn(float x){
    unsigned u = __float_as_uint(x);
    unsigned r = u + 0x7fffu + ((u >> 16) & 1u);
    return (unsigned short)(r >> 16);
}
__device__ __forceinline__ void split2(float x, unsigned short& hi, unsigned short& lo){
    unsigned short h = bf16_rn(x);
    float hf = __uint_as_float(((unsigned)h) << 16);
    lo = bf16_rn(x - hf);
    hi = h;
}

// split fp32 -> (bf16 hi, bf16 lo) arrays
__global__ __launch_bounds__(256) void split_bf16_k(
    const float* __restrict__ in, unsigned short* __restrict__ hi,
    unsigned short* __restrict__ lo, int n)
{
    int i = blockIdx.x * 256 + threadIdx.x;
    if (i < n){ unsigned short h, l; split2(in[i], h, l); hi[i] = h; lo[i] = l; }
}

// ---------------- persistent cooperative LSTM scan (split-bf16 MFMA) -------------
// grid 128 wgs x 256 thr. wg owns h-dims j0..j0+3 -> 16 gate rows {gt*512+j0+d}.
// Wave wv owns batches wv*16..+15. B-frags (W slice, hi/lo) persistent in VGPRs.
// Per step: acc=xg frag; 16 k-tiles x 3 MFMA; D->LDS; 256 thr do cell math,
// c in registers; h written to global as bf16 hi/lo ping-pong; grid.sync().
__global__ __launch_bounds__(256,1) void lstm_scan_mfma(
    const float* __restrict__ xg,            // [TT][BB][GG]
    const unsigned short* __restrict__ Whi,  // [GG][HH] bf16-hi
    const unsigned short* __restrict__ Wlo,  // [GG][HH] bf16-lo
    unsigned short* __restrict__ hhi,        // [2][BB][HH] ping-pong
    unsigned short* __restrict__ hlo,        // [2][BB][HH]
    float* __restrict__ hseq,                // mode1: [BB][TT][HH]; mode0: [BB][HH]
    int mode)
{
    __shared__ float gs[BB][17];
    const int tid  = threadIdx.x;
    const int lane = tid & 63, wv = tid >> 6;
    const int wg   = blockIdx.x;
    const int j0   = wg * 4;
    const int c16  = lane & 15, kg = lane >> 4;

    // persistent B-fragments: lane holds W[grow][kt*32 + kg*8 .. +7] hi/lo
    bf16x8 wbh[16], wbl[16];
    {
        const int grow = (c16 >> 2) * HH + j0 + (c16 & 3);
        const unsigned short* ph = Whi + (size_t)grow * HH + kg * 8;
        const unsigned short* pl = Wlo + (size_t)grow * HH + kg * 8;
        #pragma unroll
        for (int kt = 0; kt < 16; kt++){
            wbh[kt] = *(const bf16x8*)(ph + kt * 32);
            wbl[kt] = *(const bf16x8*)(pl + kt * 32);
        }
    }

    const int arow = wv * 16 + c16;                    // A row (batch) this lane loads
    const int xcol = (c16 >> 2) * HH + j0 + (c16 & 3); // xg gate column
    const int b0   = wv * 16 + kg * 4;                 // D rows base (4 batches)
    const int ab   = tid >> 2, ad = tid & 3;           // activation: (batch, dim)

    float c_st = 0.f;
    cg::grid_group grid = cg::this_grid();

    for (int t = 0; t < TT; t++){
        const unsigned short* hinh  = hhi + (size_t)(t & 1) * BB * HH;
        const unsigned short* hinl  = hlo + (size_t)(t & 1) * BB * HH;
        unsigned short* houth = hhi + (size_t)((t + 1) & 1) * BB * HH;
        unsigned short* houtl = hlo + (size_t)((t + 1) & 1) * BB * HH;

        // acc init from xg (pre-added biases)
        const float* xp = xg + (size_t)t * BB * GG + xcol;
        f32x4 acc;
        acc[0] = xp[(size_t)(b0 + 0) * GG];
        acc[1] = xp[(size_t)(b0 + 1) * GG];
        acc[2] = xp[(size_t)(b0 + 2) * GG];
        acc[3] = xp[(size_t)(b0 + 3) * GG];

        const unsigned short* pah = hinh + (size_t)arow * HH + kg * 8;
        const unsigned short* pal = hinl + (size_t)arow * HH + kg * 8;
        #pragma unroll
        for (int kt = 0; kt < 16; kt++){
            bf16x8 a_h = *(const bf16x8*)(pah + kt * 32);
            bf16x8 a_l = *(const bf16x8*)(pal + kt * 32);
            acc = __builtin_amdgcn_mfma_f32_16x16x32_bf16(a_h, wbh[kt], acc, 0, 0, 0);
            acc = __builtin_amdgcn_mfma_f32_16x16x32_bf16(a_h, wbl[kt], acc, 0, 0, 0);
            acc = __builtin_amdgcn_mfma_f32_16x16x32_bf16(a_l, wbh[kt], acc, 0, 0, 0);
        }
        // D -> LDS (lane holds D[b0+r][c16])
        gs[b0 + 0][c16] = acc[0];
        gs[b0 + 1][c16] = acc[1];
        gs[b0 + 2][c16] = acc[2];
        gs[b0 + 3][c16] = acc[3];
        __syncthreads();
        {
            float gi = gs[ab][ad], gf = gs[ab][4 + ad], gg = gs[ab][8 + ad], go = gs[ab][12 + ad];
            gi = 1.f / (1.f + expf(-gi));
            gf = 1.f / (1.f + expf(-gf));
            gg = tanhf(gg);
            go = 1.f / (1.f + expf(-go));
            c_st = gf * c_st + gi * gg;
            float h = go * tanhf(c_st);
            unsigned short hb, lb; split2(h, hb, lb);
            houth[(size_t)ab * HH + j0 + ad] = hb;
            houtl[(size_t)ab * HH + j0 + ad] = lb;
            if (mode) hseq[(size_t)ab * TT * HH + (size_t)t * HH + j0 + ad] = h;
            else      hseq[(size_t)ab * HH + j0 + ad] = h;
        }
        grid.sync();
    }
}

// ---------------- fp32 input-projection GEMM ----------
__global__ __launch_bounds__(256,2) void gemm_xg(
    const float* __restrict__ A, const int* __restrict__ gather,
    const float* __restrict__ Bw, const float* __restrict__ bias1,
    const float* __restrict__ bias2, float* __restrict__ out, int K)
{
    __shared__ float As[32][132];
    __shared__ float Bs[32][132];
    const int tid = threadIdx.x;
    const int row0 = blockIdx.y * 128, col0 = blockIdx.x * 128;
    const int tx = tid & 15, ty = tid >> 4;
    float acc[8][8];
    #pragma unroll
    for (int i=0;i<8;i++)
        #pragma unroll
        for (int j=0;j<8;j++) acc[i][j]=0.f;

    for (int k0=0;k0<K;k0+=32){
        #pragma unroll
        for (int i=0;i<4;i++){
            int f = tid + i*256;
            int r = f>>3, kq = f&7;
            const int grow = row0 + r;
            const float* src = gather ? (A + (size_t)gather[grow]*K)
                                      : (A + (size_t)grow*K);
            float4 v = *(const float4*)(src + k0 + kq*4);
            As[kq*4+0][r]=v.x; As[kq*4+1][r]=v.y; As[kq*4+2][r]=v.z; As[kq*4+3][r]=v.w;
        }
        #pragma unroll
        for (int i=0;i<4;i++){
            int f = tid + i*256;
            int r = f>>3, kq = f&7;
            const float* src = Bw + (size_t)(col0 + r)*K;
            float4 v = *(const float4*)(src + k0 + kq*4);
            Bs[kq*4+0][r]=v.x; Bs[kq*4+1][r]=v.y; Bs[kq*4+2][r]=v.z; Bs[kq*4+3][r]=v.w;
        }
        __syncthreads();
        #pragma unroll
        for (int kk=0;kk<32;kk++){
            float4 a03 = *(float4*)&As[kk][ty*8];
            float4 a47 = *(float4*)&As[kk][ty*8+4];
            float4 b03 = *(float4*)&Bs[kk][tx*8];
            float4 b47 = *(float4*)&Bs[kk][tx*8+4];
            float a[8] = {a03.x,a03.y,a03.z,a03.w,a47.x,a47.y,a47.z,a47.w};
            float b[8] = {b03.x,b03.y,b03.z,b03.w,b47.x,b47.y,b47.z,b47.w};
            #pragma unroll
            for (int i=0;i<8;i++)
                #pragma unroll
                for (int j=0;j<8;j++) acc[i][j] += a[i]*b[j];
        }
        __syncthreads();
    }
    #pragma unroll
    for (int i=0;i<8;i++){
        int r = row0 + ty*8 + i;
        int b = r >> 8, t = r & 255;
        float* orow = out + (size_t)(t*BB + b)*GG + col0 + tx*8;
        #pragma unroll
        for (int j=0;j<8;j++){
            int col = col0 + tx*8 + j;
            orow[j] = acc[i][j] + bias1[col] + bias2[col];
        }
    }
}

// logits: out[b][v] = sum_k h[b][k]*W[v][k] + bias[v]; M=64, N=50257, K=512
__global__ __launch_bounds__(256) void gemm_logits(
    const float* __restrict__ hlast, const float* __restrict__ W,
    const float* __restrict__ bias, float* __restrict__ out)
{
    __shared__ float As[32][68];
    __shared__ float Bs[32][68];
    const int tid = threadIdx.x;
    const int col0 = blockIdx.x * 64;
    const int tx = tid & 15, ty = tid >> 4;
    float acc[4][4];
    #pragma unroll
    for (int i=0;i<4;i++)
        #pragma unroll
        for (int j=0;j<4;j++) acc[i][j]=0.f;

    for (int k0=0;k0<HH;k0+=32){
        #pragma unroll
        for (int i=0;i<2;i++){
            int f = tid + i*256;
            int r = f>>3, kq = f&7;
            float4 v = *(const float4*)(hlast + (size_t)r*HH + k0 + kq*4);
            As[kq*4+0][r]=v.x; As[kq*4+1][r]=v.y; As[kq*4+2][r]=v.z; As[kq*4+3][r]=v.w;
        }
        #pragma unroll
        for (int i=0;i<2;i++){
            int f = tid + i*256;
            int r = f>>3, kq = f&7;
            int vrow = col0 + r;
            float4 v = make_float4(0.f,0.f,0.f,0.f);
            if (vrow < NCLS) v = *(const float4*)(W + (size_t)vrow*HH + k0 + kq*4);
            Bs[kq*4+0][r]=v.x; Bs[kq*4+1][r]=v.y; Bs[kq*4+2][r]=v.z; Bs[kq*4+3][r]=v.w;
        }
        __syncthreads();
        #pragma unroll
        for (int kk=0;kk<32;kk++){
            float4 a4 = *(float4*)&As[kk][ty*4];
            float4 b4 = *(float4*)&Bs[kk][tx*4];
            float a[4] = {a4.x,a4.y,a4.z,a4.w};
            float b[4] = {b4.x,b4.y,b4.z,b4.w};
            #pragma unroll
            for (int i=0;i<4;i++)
                #pragma unroll
                for (int j=0;j<4;j++) acc[i][j] += a[i]*b[j];
        }
        __syncthreads();
    }
    #pragma unroll
    for (int i=0;i<4;i++){
        int b = ty*4 + i;
        #pragma unroll
        for (int j=0;j<4;j++){
            int v = col0 + tx*4 + j;
            if (v < NCLS) out[(size_t)b*NCLS + v] = acc[i][j] + bias[v];
        }
    }
}

extern "C" void kernel_launch(void* const* d_in, const int* in_sizes, int n_in,
                              void* d_out, int out_size, void* d_ws, size_t ws_size,
                              hipStream_t stream)
{
    const int*   X     = (const int*)  d_in[0];
    const float* emb   = (const float*)d_in[1];
    const float* w_ih0 = (const float*)d_in[2];
    const float* w_hh0 = (const float*)d_in[3];
    const float* b_ih0 = (const float*)d_in[4];
    const float* b_hh0 = (const float*)d_in[5];
    const float* w_ih1 = (const float*)d_in[6];
    const float* w_hh1 = (const float*)d_in[7];
    const float* b_ih1 = (const float*)d_in[8];
    const float* b_hh1 = (const float*)d_in[9];
    const float* Wout  = (const float*)d_in[10];
    const float* bout  = (const float*)d_in[11];
    float* out = (float*)d_out;

    float* ws    = (float*)d_ws;
    float* xg    = ws;                          // 33,554,432 f
    float* h0seq = ws + 33554432;               // 8,388,608 f
    float* hlast = ws + 41943040;               // 32,768 f
    unsigned short* Whi0 = (unsigned short*)(ws + 41975808);  // 1M shorts (524288 f)
    unsigned short* Wlo0 = (unsigned short*)(ws + 42500096);
    unsigned short* Whi1 = (unsigned short*)(ws + 43024384);
    unsigned short* Wlo1 = (unsigned short*)(ws + 43548672);
    unsigned short* hhi  = (unsigned short*)(ws + 44072960);  // 2*BB*HH shorts
    unsigned short* hlo  = (unsigned short*)(ws + 44105728);
    // total 44,138,496 floats = 176.6 MB

    dim3 gemmGrid(16, 128);

    // weight splits (once per call)
    split_bf16_k<<<4096, 256, 0, stream>>>(w_hh0, Whi0, Wlo0, GG*HH);
    split_bf16_k<<<4096, 256, 0, stream>>>(w_hh1, Whi1, Wlo1, GG*HH);

    // ---- layer 0
    gemm_xg<<<gemmGrid, 256, 0, stream>>>(emb, X, w_ih0, b_ih0, b_hh0, xg, HH);
    hipMemsetAsync(hhi, 0, (size_t)2*BB*HH*sizeof(unsigned short), stream);
    hipMemsetAsync(hlo, 0, (size_t)2*BB*HH*sizeof(unsigned short), stream);
    {
        const float* a0 = xg; const unsigned short *a1 = Whi0, *a2 = Wlo0;
        unsigned short *a3 = hhi, *a4 = hlo; float* a5 = h0seq; int a6 = 1;
        void* args[] = {&a0,&a1,&a2,&a3,&a4,&a5,&a6};
        hipLaunchCooperativeKernel((void*)lstm_scan_mfma, dim3(128), dim3(256), args, 0, stream);
    }
    // ---- layer 1
    gemm_xg<<<gemmGrid, 256, 0, stream>>>(h0seq, nullptr, w_ih1, b_ih1, b_hh1, xg, HH);
    hipMemsetAsync(hhi, 0, (size_t)2*BB*HH*sizeof(unsigned short), stream);
    hipMemsetAsync(hlo, 0, (size_t)2*BB*HH*sizeof(unsigned short), stream);
    {
        const float* a0 = xg; const unsigned short *a1 = Whi1, *a2 = Wlo1;
        unsigned short *a3 = hhi, *a4 = hlo; float* a5 = hlast; int a6 = 0;
        void* args[] = {&a0,&a1,&a2,&a3,&a4,&a5,&a6};
        hipLaunchCooperativeKernel((void*)lstm_scan_mfma, dim3(128), dim3(256), args, 0, stream);
    }
    gemm_logits<<<786, 256, 0, stream>>>(hlast, Wout, bout, out);
}

// Round 8
// 8586.320 us; speedup vs baseline: 1.4611x; 1.4611x over previous
//
#include <hip/hip_runtime.h>
#include <cstdint>
#include <cstddef>

#define HH 512
#define BB 64
#define TT 256
#define GG 2048   // 4*HH
#define NCLS 50257
#define NWG 128   // scan grid size

typedef __attribute__((ext_vector_type(4))) float f32x4;
typedef __attribute__((ext_vector_type(8))) short bf16x8;

__device__ __forceinline__ unsigned short bf16_rn(float x){
    unsigned u = __float_as_uint(x);
    unsigned r = u + 0x7fffu + ((u >> 16) & 1u);
    return (unsigned short)(r >> 16);
}
__device__ __forceinline__ void split2(float x, unsigned short& hi, unsigned short& lo){
    unsigned short h = bf16_rn(x);
    float hf = __uint_as_float(((unsigned)h) << 16);
    lo = bf16_rn(x - hf);
    hi = h;
}

// split fp32 -> (bf16 hi, bf16 lo) arrays
__global__ __launch_bounds__(256) void split_bf16_k(
    const float* __restrict__ in, unsigned short* __restrict__ hi,
    unsigned short* __restrict__ lo, int n)
{
    int i = blockIdx.x * 256 + threadIdx.x;
    if (i < n){ unsigned short h, l; split2(in[i], h, l); hi[i] = h; lo[i] = l; }
}

// ---------------- persistent LSTM scan (split-bf16 MFMA, custom grid barrier) ----
// grid 128 wgs x 256 thr. wg owns h-dims j0..j0+3 -> 16 gate rows {gt*512+j0+d}.
// Wave wv owns batches wv*16..+15. B-frags (W slice, hi/lo) persistent in VGPRs.
// Per step: acc=xg frag; 16 k-tiles x 3 MFMA; D->LDS; cell math; h ping-pong;
// then monotonic-counter grid barrier (replaces cg::grid.sync, which cost ~22us).
__global__ __launch_bounds__(256,1) void lstm_scan_mfma(
    const float* __restrict__ xg,            // [TT][BB][GG]
    const unsigned short* __restrict__ Whi,  // [GG][HH] bf16-hi
    const unsigned short* __restrict__ Wlo,  // [GG][HH] bf16-lo
    unsigned short* __restrict__ hhi,        // [2][BB][HH] ping-pong
    unsigned short* __restrict__ hlo,        // [2][BB][HH]
    float* __restrict__ hseq,                // mode1: [BB][TT][HH]; mode0: [BB][HH]
    int* __restrict__ bar,                   // zeroed counter (own cacheline)
    int mode)
{
    __shared__ float gs[BB][17];
    const int tid  = threadIdx.x;
    const int lane = tid & 63, wv = tid >> 6;
    const int wg   = blockIdx.x;
    const int j0   = wg * 4;
    const int c16  = lane & 15, kg = lane >> 4;

    // persistent B-fragments: lane holds W[grow][kt*32 + kg*8 .. +7] hi/lo
    bf16x8 wbh[16], wbl[16];
    {
        const int grow = (c16 >> 2) * HH + j0 + (c16 & 3);
        const unsigned short* ph = Whi + (size_t)grow * HH + kg * 8;
        const unsigned short* pl = Wlo + (size_t)grow * HH + kg * 8;
        #pragma unroll
        for (int kt = 0; kt < 16; kt++){
            wbh[kt] = *(const bf16x8*)(ph + kt * 32);
            wbl[kt] = *(const bf16x8*)(pl + kt * 32);
        }
    }

    const int arow = wv * 16 + c16;                    // A row (batch) this lane loads
    const int xcol = (c16 >> 2) * HH + j0 + (c16 & 3); // xg gate column
    const int b0   = wv * 16 + kg * 4;                 // D rows base (4 batches)
    const int ab   = tid >> 2, ad = tid & 3;           // activation: (batch, dim)

    float c_st = 0.f;

    for (int t = 0; t < TT; t++){
        const unsigned short* hinh  = hhi + (size_t)(t & 1) * BB * HH;
        const unsigned short* hinl  = hlo + (size_t)(t & 1) * BB * HH;
        unsigned short* houth = hhi + (size_t)((t + 1) & 1) * BB * HH;
        unsigned short* houtl = hlo + (size_t)((t + 1) & 1) * BB * HH;

        // acc init from xg (pre-added biases)
        const float* xp = xg + (size_t)t * BB * GG + xcol;
        f32x4 acc;
        acc[0] = xp[(size_t)(b0 + 0) * GG];
        acc[1] = xp[(size_t)(b0 + 1) * GG];
        acc[2] = xp[(size_t)(b0 + 2) * GG];
        acc[3] = xp[(size_t)(b0 + 3) * GG];

        const unsigned short* pah = hinh + (size_t)arow * HH + kg * 8;
        const unsigned short* pal = hinl + (size_t)arow * HH + kg * 8;
        #pragma unroll
        for (int kt = 0; kt < 16; kt++){
            bf16x8 a_h = *(const bf16x8*)(pah + kt * 32);
            bf16x8 a_l = *(const bf16x8*)(pal + kt * 32);
            acc = __builtin_amdgcn_mfma_f32_16x16x32_bf16(a_h, wbh[kt], acc, 0, 0, 0);
            acc = __builtin_amdgcn_mfma_f32_16x16x32_bf16(a_h, wbl[kt], acc, 0, 0, 0);
            acc = __builtin_amdgcn_mfma_f32_16x16x32_bf16(a_l, wbh[kt], acc, 0, 0, 0);
        }
        // D -> LDS (lane holds D[b0+r][c16])
        gs[b0 + 0][c16] = acc[0];
        gs[b0 + 1][c16] = acc[1];
        gs[b0 + 2][c16] = acc[2];
        gs[b0 + 3][c16] = acc[3];
        __syncthreads();
        {
            float gi = gs[ab][ad], gf = gs[ab][4 + ad], gg = gs[ab][8 + ad], go = gs[ab][12 + ad];
            gi = 1.f / (1.f + expf(-gi));
            gf = 1.f / (1.f + expf(-gf));
            gg = tanhf(gg);
            go = 1.f / (1.f + expf(-go));
            c_st = gf * c_st + gi * gg;
            float h = go * tanhf(c_st);
            unsigned short hb, lb; split2(h, hb, lb);
            houth[(size_t)ab * HH + j0 + ad] = hb;
            houtl[(size_t)ab * HH + j0 + ad] = lb;
            if (mode) hseq[(size_t)ab * TT * HH + (size_t)t * HH + j0 + ad] = h;
            else      hseq[(size_t)ab * HH + j0 + ad] = h;
        }
        // ---- custom grid barrier (monotonic counter, agent-scope) ----
        __syncthreads();   // all wg stores drained (vmcnt 0 before s_barrier)
        if (tid == 0){
            __builtin_amdgcn_fence(__ATOMIC_RELEASE, "agent");   // flush h to coherent point
            __hip_atomic_fetch_add(bar, 1, __ATOMIC_RELAXED, __HIP_MEMORY_SCOPE_AGENT);
            const int target = NWG * (t + 1);
            while (__hip_atomic_load(bar, __ATOMIC_RELAXED, __HIP_MEMORY_SCOPE_AGENT) < target)
                __builtin_amdgcn_s_sleep(1);
            __builtin_amdgcn_fence(__ATOMIC_ACQUIRE, "agent");   // inv stale h lines (L1/L2)
        }
        __syncthreads();
    }
}

// ---------------- fp32 input-projection GEMM ----------
__global__ __launch_bounds__(256,2) void gemm_xg(
    const float* __restrict__ A, const int* __restrict__ gather,
    const float* __restrict__ Bw, const float* __restrict__ bias1,
    const float* __restrict__ bias2, float* __restrict__ out, int K)
{
    __shared__ float As[32][132];
    __shared__ float Bs[32][132];
    const int tid = threadIdx.x;
    const int row0 = blockIdx.y * 128, col0 = blockIdx.x * 128;
    const int tx = tid & 15, ty = tid >> 4;
    float acc[8][8];
    #pragma unroll
    for (int i=0;i<8;i++)
        #pragma unroll
        for (int j=0;j<8;j++) acc[i][j]=0.f;

    for (int k0=0;k0<K;k0+=32){
        #pragma unroll
        for (int i=0;i<4;i++){
            int f = tid + i*256;
            int r = f>>3, kq = f&7;
            const int grow = row0 + r;
            const float* src = gather ? (A + (size_t)gather[grow]*K)
                                      : (A + (size_t)grow*K);
            float4 v = *(const float4*)(src + k0 + kq*4);
            As[kq*4+0][r]=v.x; As[kq*4+1][r]=v.y; As[kq*4+2][r]=v.z; As[kq*4+3][r]=v.w;
        }
        #pragma unroll
        for (int i=0;i<4;i++){
            int f = tid + i*256;
            int r = f>>3, kq = f&7;
            const float* src = Bw + (size_t)(col0 + r)*K;
            float4 v = *(const float4*)(src + k0 + kq*4);
            Bs[kq*4+0][r]=v.x; Bs[kq*4+1][r]=v.y; Bs[kq*4+2][r]=v.z; Bs[kq*4+3][r]=v.w;
        }
        __syncthreads();
        #pragma unroll
        for (int kk=0;kk<32;kk++){
            float4 a03 = *(float4*)&As[kk][ty*8];
            float4 a47 = *(float4*)&As[kk][ty*8+4];
            float4 b03 = *(float4*)&Bs[kk][tx*8];
            float4 b47 = *(float4*)&Bs[kk][tx*8+4];
            float a[8] = {a03.x,a03.y,a03.z,a03.w,a47.x,a47.y,a47.z,a47.w};
            float b[8] = {b03.x,b03.y,b03.z,b03.w,b47.x,b47.y,b47.z,b47.w};
            #pragma unroll
            for (int i=0;i<8;i++)
                #pragma unroll
                for (int j=0;j<8;j++) acc[i][j] += a[i]*b[j];
        }
        __syncthreads();
    }
    #pragma unroll
    for (int i=0;i<8;i++){
        int r = row0 + ty*8 + i;
        int b = r >> 8, t = r & 255;
        float* orow = out + (size_t)(t*BB + b)*GG + col0 + tx*8;
        #pragma unroll
        for (int j=0;j<8;j++){
            int col = col0 + tx*8 + j;
            orow[j] = acc[i][j] + bias1[col] + bias2[col];
        }
    }
}

// logits: out[b][v] = sum_k h[b][k]*W[v][k] + bias[v]; M=64, N=50257, K=512
__global__ __launch_bounds__(256) void gemm_logits(
    const float* __restrict__ hlast, const float* __restrict__ W,
    const float* __restrict__ bias, float* __restrict__ out)
{
    __shared__ float As[32][68];
    __shared__ float Bs[32][68];
    const int tid = threadIdx.x;
    const int col0 = blockIdx.x * 64;
    const int tx = tid & 15, ty = tid >> 4;
    float acc[4][4];
    #pragma unroll
    for (int i=0;i<4;i++)
        #pragma unroll
        for (int j=0;j<4;j++) acc[i][j]=0.f;

    for (int k0=0;k0<HH;k0+=32){
        #pragma unroll
        for (int i=0;i<2;i++){
            int f = tid + i*256;
            int r = f>>3, kq = f&7;
            float4 v = *(const float4*)(hlast + (size_t)r*HH + k0 + kq*4);
            As[kq*4+0][r]=v.x; As[kq*4+1][r]=v.y; As[kq*4+2][r]=v.z; As[kq*4+3][r]=v.w;
        }
        #pragma unroll
        for (int i=0;i<2;i++){
            int f = tid + i*256;
            int r = f>>3, kq = f&7;
            int vrow = col0 + r;
            float4 v = make_float4(0.f,0.f,0.f,0.f);
            if (vrow < NCLS) v = *(const float4*)(W + (size_t)vrow*HH + k0 + kq*4);
            Bs[kq*4+0][r]=v.x; Bs[kq*4+1][r]=v.y; Bs[kq*4+2][r]=v.z; Bs[kq*4+3][r]=v.w;
        }
        __syncthreads();
        #pragma unroll
        for (int kk=0;kk<32;kk++){
            float4 a4 = *(float4*)&As[kk][ty*4];
            float4 b4 = *(float4*)&Bs[kk][tx*4];
            float a[4] = {a4.x,a4.y,a4.z,a4.w};
            float b[4] = {b4.x,b4.y,b4.z,b4.w};
            #pragma unroll
            for (int i=0;i<4;i++)
                #pragma unroll
                for (int j=0;j<4;j++) acc[i][j] += a[i]*b[j];
        }
        __syncthreads();
    }
    #pragma unroll
    for (int i=0;i<4;i++){
        int b = ty*4 + i;
        #pragma unroll
        for (int j=0;j<4;j++){
            int v = col0 + tx*4 + j;
            if (v < NCLS) out[(size_t)b*NCLS + v] = acc[i][j] + bias[v];
        }
    }
}

extern "C" void kernel_launch(void* const* d_in, const int* in_sizes, int n_in,
                              void* d_out, int out_size, void* d_ws, size_t ws_size,
                              hipStream_t stream)
{
    const int*   X     = (const int*)  d_in[0];
    const float* emb   = (const float*)d_in[1];
    const float* w_ih0 = (const float*)d_in[2];
    const float* w_hh0 = (const float*)d_in[3];
    const float* b_ih0 = (const float*)d_in[4];
    const float* b_hh0 = (const float*)d_in[5];
    const float* w_ih1 = (const float*)d_in[6];
    const float* w_hh1 = (const float*)d_in[7];
    const float* b_ih1 = (const float*)d_in[8];
    const float* b_hh1 = (const float*)d_in[9];
    const float* Wout  = (const float*)d_in[10];
    const float* bout  = (const float*)d_in[11];
    float* out = (float*)d_out;

    float* ws    = (float*)d_ws;
    float* xg    = ws;                          // 33,554,432 f
    float* h0seq = ws + 33554432;               // 8,388,608 f
    float* hlast = ws + 41943040;               // 32,768 f
    unsigned short* Whi0 = (unsigned short*)(ws + 41975808);  // 1M shorts (524288 f)
    unsigned short* Wlo0 = (unsigned short*)(ws + 42500096);
    unsigned short* Whi1 = (unsigned short*)(ws + 43024384);
    unsigned short* Wlo1 = (unsigned short*)(ws + 43548672);
    unsigned short* hhi  = (unsigned short*)(ws + 44072960);  // 2*BB*HH shorts
    unsigned short* hlo  = (unsigned short*)(ws + 44105728);
    int*            bar  = (int*)(ws + 44138496);             // barrier counter
    // total ~176.6 MB of d_ws

    dim3 gemmGrid(16, 128);

    // weight splits (once per call)
    split_bf16_k<<<4096, 256, 0, stream>>>(w_hh0, Whi0, Wlo0, GG*HH);
    split_bf16_k<<<4096, 256, 0, stream>>>(w_hh1, Whi1, Wlo1, GG*HH);

    // ---- layer 0
    gemm_xg<<<gemmGrid, 256, 0, stream>>>(emb, X, w_ih0, b_ih0, b_hh0, xg, HH);
    hipMemsetAsync(hhi, 0, (size_t)2*BB*HH*sizeof(unsigned short), stream);
    hipMemsetAsync(hlo, 0, (size_t)2*BB*HH*sizeof(unsigned short), stream);
    hipMemsetAsync(bar, 0, 256, stream);
    {
        const float* a0 = xg; const unsigned short *a1 = Whi0, *a2 = Wlo0;
        unsigned short *a3 = hhi, *a4 = hlo; float* a5 = h0seq; int* a6 = bar; int a7 = 1;
        void* args[] = {&a0,&a1,&a2,&a3,&a4,&a5,&a6,&a7};
        hipLaunchCooperativeKernel((void*)lstm_scan_mfma, dim3(NWG), dim3(256), args, 0, stream);
    }
    // ---- layer 1
    gemm_xg<<<gemmGrid, 256, 0, stream>>>(h0seq, nullptr, w_ih1, b_ih1, b_hh1, xg, HH);
    hipMemsetAsync(hhi, 0, (size_t)2*BB*HH*sizeof(unsigned short), stream);
    hipMemsetAsync(hlo, 0, (size_t)2*BB*HH*sizeof(unsigned short), stream);
    hipMemsetAsync(bar, 0, 256, stream);
    {
        const float* a0 = xg; const unsigned short *a1 = Whi1, *a2 = Wlo1;
        unsigned short *a3 = hhi, *a4 = hlo; float* a5 = hlast; int* a6 = bar; int a7 = 0;
        void* args[] = {&a0,&a1,&a2,&a3,&a4,&a5,&a6,&a7};
        hipLaunchCooperativeKernel((void*)lstm_scan_mfma, dim3(NWG), dim3(256), args, 0, stream);
    }
    gemm_logits<<<786, 256, 0, stream>>>(hlast, Wout, bout, out);
}

// Round 9
// 4944.080 us; speedup vs baseline: 2.5375x; 1.7367x over previous
//
#include <hip/hip_runtime.h>
#include <cstdint>
#include <cstddef>

#define HH 512
#define BB 64
#define TT 256
#define GG 2048   // 4*HH
#define NCLS 50257
#define NWG 128   // scan grid size (16 wgs per group x 8 groups)

typedef __attribute__((ext_vector_type(4))) float f32x4;
typedef __attribute__((ext_vector_type(8))) short bf16x8;
typedef __attribute__((ext_vector_type(4))) unsigned int u32x4;
typedef __attribute__((ext_vector_type(8))) unsigned int u32x8;

__device__ __forceinline__ unsigned short bf16_rn(float x){
    unsigned u = __float_as_uint(x);
    unsigned r = u + 0x7fffu + ((u >> 16) & 1u);
    return (unsigned short)(r >> 16);
}
__device__ __forceinline__ void split2(float x, unsigned short& hi, unsigned short& lo){
    unsigned short h = bf16_rn(x);
    float hf = __uint_as_float(((unsigned)h) << 16);
    lo = bf16_rn(x - hf);
    hi = h;
}
__device__ __forceinline__ bf16x8 mk8(unsigned a, unsigned b, unsigned c, unsigned d){
    u32x4 t; t[0]=a; t[1]=b; t[2]=c; t[3]=d;
    return __builtin_bit_cast(bf16x8, t);
}

// split fp32 -> (bf16 hi, bf16 lo) arrays
__global__ __launch_bounds__(256) void split_bf16_k(
    const float* __restrict__ in, unsigned short* __restrict__ hi,
    unsigned short* __restrict__ lo, int n)
{
    int i = blockIdx.x * 256 + threadIdx.x;
    if (i < n){ unsigned short h, l; split2(in[i], h, l); hi[i] = h; lo[i] = l; }
}

// ---------------- persistent LSTM scan (split-bf16 MFMA, epoch barrier) ----------
// 128 wgs x 256 thr. wg owns h-dims j0..j0+3 -> 16 gate rows. Whh slice hi/lo from
// global each step (L2/IF). h ping-pong: packed u32 (lo16|hi16), STORES are relaxed
// agent atomics (sc1 write-through -> IF; release = syncthreads vmcnt drain, no wbl2).
// Barrier: hierarchical monotonic counters + epoch broadcast line; spinners poll
// epoch only (no RMW/poll contention). xg prefetch overlaps the spin. Acquire =
// buffer_inv (tid0) as in round 8.
__global__ __launch_bounds__(256,1) void lstm_scan_mfma(
    const float* __restrict__ xg,            // [TT][BB][GG]
    const unsigned short* __restrict__ Whi,  // [GG][HH] bf16-hi
    const unsigned short* __restrict__ Wlo,  // [GG][HH] bf16-lo
    unsigned* __restrict__ hpk,              // [2][BB][HH] packed (lo<<16)|hi
    float* __restrict__ hseq,                // mode1: [BB][TT][HH]; mode0: [BB][HH]
    int* __restrict__ bar,                   // zeroed: [0]=epoch, 32+g*32 groups, 288 root
    int mode)
{
    __shared__ float gs[BB][17];
    const int tid  = threadIdx.x;
    const int lane = tid & 63, wv = tid >> 6;
    const int wg   = blockIdx.x;
    const int j0   = wg * 4;
    const int c16  = lane & 15, kg = lane >> 4;

    // persistent B-fragments: lane holds W[grow][kt*32 + kg*8 .. +7] hi/lo
    bf16x8 wbh[16], wbl[16];
    {
        const int grow = (c16 >> 2) * HH + j0 + (c16 & 3);
        const unsigned short* ph = Whi + (size_t)grow * HH + kg * 8;
        const unsigned short* pl = Wlo + (size_t)grow * HH + kg * 8;
        #pragma unroll
        for (int kt = 0; kt < 16; kt++){
            wbh[kt] = *(const bf16x8*)(ph + kt * 32);
            wbl[kt] = *(const bf16x8*)(pl + kt * 32);
        }
    }

    const int arow = wv * 16 + c16;                    // A row (batch) this lane loads
    const int xcol = (c16 >> 2) * HH + j0 + (c16 & 3); // xg gate column
    const int b0   = wv * 16 + kg * 4;                 // D rows base (4 batches)
    const int ab   = tid >> 2, ad = tid & 3;           // activation: (batch, dim)

    float c_st = 0.f;

    // prime xg accumulator for t=0
    f32x4 cur;
    {
        const float* xp = xg + xcol;
        cur[0] = xp[(size_t)(b0 + 0) * GG];
        cur[1] = xp[(size_t)(b0 + 1) * GG];
        cur[2] = xp[(size_t)(b0 + 2) * GG];
        cur[3] = xp[(size_t)(b0 + 3) * GG];
    }

    for (int t = 0; t < TT; t++){
        const unsigned* hin  = hpk + (size_t)(t & 1) * BB * HH;
        unsigned*       hout = hpk + (size_t)((t + 1) & 1) * BB * HH;

        f32x4 acc = cur;
        const unsigned* pa = hin + (size_t)arow * HH + kg * 8;
        #pragma unroll
        for (int kt = 0; kt < 16; kt++){
            u32x8 w = *(const u32x8*)(pa + kt * 32);
            // unpack: word i = (lo16(dim i)<<16) | hi16(dim i)
            unsigned h01 = __builtin_amdgcn_perm(w[1], w[0], 0x05040100u);
            unsigned h23 = __builtin_amdgcn_perm(w[3], w[2], 0x05040100u);
            unsigned h45 = __builtin_amdgcn_perm(w[5], w[4], 0x05040100u);
            unsigned h67 = __builtin_amdgcn_perm(w[7], w[6], 0x05040100u);
            unsigned l01 = __builtin_amdgcn_perm(w[1], w[0], 0x07060302u);
            unsigned l23 = __builtin_amdgcn_perm(w[3], w[2], 0x07060302u);
            unsigned l45 = __builtin_amdgcn_perm(w[5], w[4], 0x07060302u);
            unsigned l67 = __builtin_amdgcn_perm(w[7], w[6], 0x07060302u);
            bf16x8 a_h = mk8(h01, h23, h45, h67);
            bf16x8 a_l = mk8(l01, l23, l45, l67);
            acc = __builtin_amdgcn_mfma_f32_16x16x32_bf16(a_h, wbh[kt], acc, 0, 0, 0);
            acc = __builtin_amdgcn_mfma_f32_16x16x32_bf16(a_h, wbl[kt], acc, 0, 0, 0);
            acc = __builtin_amdgcn_mfma_f32_16x16x32_bf16(a_l, wbh[kt], acc, 0, 0, 0);
        }
        // D -> LDS (lane holds D[b0+r][c16])
        gs[b0 + 0][c16] = acc[0];
        gs[b0 + 1][c16] = acc[1];
        gs[b0 + 2][c16] = acc[2];
        gs[b0 + 3][c16] = acc[3];
        __syncthreads();
        {
            float gi = gs[ab][ad], gf = gs[ab][4 + ad], gg = gs[ab][8 + ad], go = gs[ab][12 + ad];
            gi = 1.f / (1.f + expf(-gi));
            gf = 1.f / (1.f + expf(-gf));
            gg = tanhf(gg);
            go = 1.f / (1.f + expf(-go));
            c_st = gf * c_st + gi * gg;
            float h = go * tanhf(c_st);
            unsigned short hb, lb; split2(h, hb, lb);
            unsigned pk = (((unsigned)lb) << 16) | (unsigned)hb;
            // write-through to IF (coherent without wbl2)
            __hip_atomic_store(&hout[(size_t)ab * HH + j0 + ad], pk,
                               __ATOMIC_RELAXED, __HIP_MEMORY_SCOPE_AGENT);
            if (mode) hseq[(size_t)ab * TT * HH + (size_t)t * HH + j0 + ad] = h;
            else      hseq[(size_t)ab * HH + j0 + ad] = h;
        }
        // ---- epoch barrier ----
        __syncthreads();   // drains vmcnt(0): h sc1-stores are at IF (release)
        if (tid == 0){
            const int g = wg & 7;
            int old = __hip_atomic_fetch_add(bar + 32 + g * 32, 1,
                        __ATOMIC_RELAXED, __HIP_MEMORY_SCOPE_AGENT);
            if (old == (NWG / 8) * (t + 1) - 1){
                int r = __hip_atomic_fetch_add(bar + 288, 1,
                            __ATOMIC_RELAXED, __HIP_MEMORY_SCOPE_AGENT);
                if (r == 8 * (t + 1) - 1){
                    __hip_atomic_store(bar, t + 1,
                        __ATOMIC_RELAXED, __HIP_MEMORY_SCOPE_AGENT);
                }
            }
        }
        // prefetch next-step xg into regs (overlaps the spin below)
        {
            const int tp = (t + 1 < TT) ? t + 1 : t;
            const float* xp = xg + (size_t)tp * BB * GG + xcol;
            cur[0] = xp[(size_t)(b0 + 0) * GG];
            cur[1] = xp[(size_t)(b0 + 1) * GG];
            cur[2] = xp[(size_t)(b0 + 2) * GG];
            cur[3] = xp[(size_t)(b0 + 3) * GG];
        }
        if (tid == 0){
            while (__hip_atomic_load(bar, __ATOMIC_RELAXED, __HIP_MEMORY_SCOPE_AGENT) < t + 1)
                __builtin_amdgcn_s_sleep(2);
            __builtin_amdgcn_fence(__ATOMIC_ACQUIRE, "agent");   // inv stale h lines
        }
        __syncthreads();
    }
}

// ---------------- fp32 input-projection GEMM ----------
__global__ __launch_bounds__(256,2) void gemm_xg(
    const float* __restrict__ A, const int* __restrict__ gather,
    const float* __restrict__ Bw, const float* __restrict__ bias1,
    const float* __restrict__ bias2, float* __restrict__ out, int K)
{
    __shared__ float As[32][132];
    __shared__ float Bs[32][132];
    const int tid = threadIdx.x;
    const int row0 = blockIdx.y * 128, col0 = blockIdx.x * 128;
    const int tx = tid & 15, ty = tid >> 4;
    float acc[8][8];
    #pragma unroll
    for (int i=0;i<8;i++)
        #pragma unroll
        for (int j=0;j<8;j++) acc[i][j]=0.f;

    for (int k0=0;k0<K;k0+=32){
        #pragma unroll
        for (int i=0;i<4;i++){
            int f = tid + i*256;
            int r = f>>3, kq = f&7;
            const int grow = row0 + r;
            const float* src = gather ? (A + (size_t)gather[grow]*K)
                                      : (A + (size_t)grow*K);
            float4 v = *(const float4*)(src + k0 + kq*4);
            As[kq*4+0][r]=v.x; As[kq*4+1][r]=v.y; As[kq*4+2][r]=v.z; As[kq*4+3][r]=v.w;
        }
        #pragma unroll
        for (int i=0;i<4;i++){
            int f = tid + i*256;
            int r = f>>3, kq = f&7;
            const float* src = Bw + (size_t)(col0 + r)*K;
            float4 v = *(const float4*)(src + k0 + kq*4);
            Bs[kq*4+0][r]=v.x; Bs[kq*4+1][r]=v.y; Bs[kq*4+2][r]=v.z; Bs[kq*4+3][r]=v.w;
        }
        __syncthreads();
        #pragma unroll
        for (int kk=0;kk<32;kk++){
            float4 a03 = *(float4*)&As[kk][ty*8];
            float4 a47 = *(float4*)&As[kk][ty*8+4];
            float4 b03 = *(float4*)&Bs[kk][tx*8];
            float4 b47 = *(float4*)&Bs[kk][tx*8+4];
            float a[8] = {a03.x,a03.y,a03.z,a03.w,a47.x,a47.y,a47.z,a47.w};
            float b[8] = {b03.x,b03.y,b03.z,b03.w,b47.x,b47.y,b47.z,b47.w};
            #pragma unroll
            for (int i=0;i<8;i++)
                #pragma unroll
                for (int j=0;j<8;j++) acc[i][j] += a[i]*b[j];
        }
        __syncthreads();
    }
    #pragma unroll
    for (int i=0;i<8;i++){
        int r = row0 + ty*8 + i;
        int b = r >> 8, t = r & 255;
        float* orow = out + (size_t)(t*BB + b)*GG + col0 + tx*8;
        #pragma unroll
        for (int j=0;j<8;j++){
            int col = col0 + tx*8 + j;
            orow[j] = acc[i][j] + bias1[col] + bias2[col];
        }
    }
}

// logits: out[b][v] = sum_k h[b][k]*W[v][k] + bias[v]; M=64, N=50257, K=512
__global__ __launch_bounds__(256) void gemm_logits(
    const float* __restrict__ hlast, const float* __restrict__ W,
    const float* __restrict__ bias, float* __restrict__ out)
{
    __shared__ float As[32][68];
    __shared__ float Bs[32][68];
    const int tid = threadIdx.x;
    const int col0 = blockIdx.x * 64;
    const int tx = tid & 15, ty = tid >> 4;
    float acc[4][4];
    #pragma unroll
    for (int i=0;i<4;i++)
        #pragma unroll
        for (int j=0;j<4;j++) acc[i][j]=0.f;

    for (int k0=0;k0<HH;k0+=32){
        #pragma unroll
        for (int i=0;i<2;i++){
            int f = tid + i*256;
            int r = f>>3, kq = f&7;
            float4 v = *(const float4*)(hlast + (size_t)r*HH + k0 + kq*4);
            As[kq*4+0][r]=v.x; As[kq*4+1][r]=v.y; As[kq*4+2][r]=v.z; As[kq*4+3][r]=v.w;
        }
        #pragma unroll
        for (int i=0;i<2;i++){
            int f = tid + i*256;
            int r = f>>3, kq = f&7;
            int vrow = col0 + r;
            float4 v = make_float4(0.f,0.f,0.f,0.f);
            if (vrow < NCLS) v = *(const float4*)(W + (size_t)vrow*HH + k0 + kq*4);
            Bs[kq*4+0][r]=v.x; Bs[kq*4+1][r]=v.y; Bs[kq*4+2][r]=v.z; Bs[kq*4+3][r]=v.w;
        }
        __syncthreads();
        #pragma unroll
        for (int kk=0;kk<32;kk++){
            float4 a4 = *(float4*)&As[kk][ty*4];
            float4 b4 = *(float4*)&Bs[kk][tx*4];
            float a[4] = {a4.x,a4.y,a4.z,a4.w};
            float b[4] = {b4.x,b4.y,b4.z,b4.w};
            #pragma unroll
            for (int i=0;i<4;i++)
                #pragma unroll
                for (int j=0;j<4;j++) acc[i][j] += a[i]*b[j];
        }
        __syncthreads();
    }
    #pragma unroll
    for (int i=0;i<4;i++){
        int b = ty*4 + i;
        #pragma unroll
        for (int j=0;j<4;j++){
            int v = col0 + tx*4 + j;
            if (v < NCLS) out[(size_t)b*NCLS + v] = acc[i][j] + bias[v];
        }
    }
}

extern "C" void kernel_launch(void* const* d_in, const int* in_sizes, int n_in,
                              void* d_out, int out_size, void* d_ws, size_t ws_size,
                              hipStream_t stream)
{
    const int*   X     = (const int*)  d_in[0];
    const float* emb   = (const float*)d_in[1];
    const float* w_ih0 = (const float*)d_in[2];
    const float* w_hh0 = (const float*)d_in[3];
    const float* b_ih0 = (const float*)d_in[4];
    const float* b_hh0 = (const float*)d_in[5];
    const float* w_ih1 = (const float*)d_in[6];
    const float* w_hh1 = (const float*)d_in[7];
    const float* b_ih1 = (const float*)d_in[8];
    const float* b_hh1 = (const float*)d_in[9];
    const float* Wout  = (const float*)d_in[10];
    const float* bout  = (const float*)d_in[11];
    float* out = (float*)d_out;

    float* ws    = (float*)d_ws;
    float* xg    = ws;                          // 33,554,432 f
    float* h0seq = ws + 33554432;               // 8,388,608 f
    float* hlast = ws + 41943040;               // 32,768 f
    unsigned short* Whi0 = (unsigned short*)(ws + 41975808);  // 1M shorts (524288 f)
    unsigned short* Wlo0 = (unsigned short*)(ws + 42500096);
    unsigned short* Whi1 = (unsigned short*)(ws + 43024384);
    unsigned short* Wlo1 = (unsigned short*)(ws + 43548672);
    unsigned*       hpk  = (unsigned*)(ws + 44072960);        // [2][64][512] u32 = 256KB
    int*            bar  = (int*)(ws + 44138496);             // barrier lines (4KB)
    // total ~176.6 MB of d_ws

    dim3 gemmGrid(16, 128);

    // weight splits (once per call)
    split_bf16_k<<<4096, 256, 0, stream>>>(w_hh0, Whi0, Wlo0, GG*HH);
    split_bf16_k<<<4096, 256, 0, stream>>>(w_hh1, Whi1, Wlo1, GG*HH);

    // ---- layer 0
    gemm_xg<<<gemmGrid, 256, 0, stream>>>(emb, X, w_ih0, b_ih0, b_hh0, xg, HH);
    hipMemsetAsync(hpk, 0, (size_t)2*BB*HH*sizeof(unsigned), stream);
    hipMemsetAsync(bar, 0, 4096, stream);
    {
        const float* a0 = xg; const unsigned short *a1 = Whi0, *a2 = Wlo0;
        unsigned* a3 = hpk; float* a4 = h0seq; int* a5 = bar; int a6 = 1;
        void* args[] = {&a0,&a1,&a2,&a3,&a4,&a5,&a6};
        hipLaunchCooperativeKernel((void*)lstm_scan_mfma, dim3(NWG), dim3(256), args, 0, stream);
    }
    // ---- layer 1
    gemm_xg<<<gemmGrid, 256, 0, stream>>>(h0seq, nullptr, w_ih1, b_ih1, b_hh1, xg, HH);
    hipMemsetAsync(hpk, 0, (size_t)2*BB*HH*sizeof(unsigned), stream);
    hipMemsetAsync(bar, 0, 4096, stream);
    {
        const float* a0 = xg; const unsigned short *a1 = Whi1, *a2 = Wlo1;
        unsigned* a3 = hpk; float* a4 = hlast; int* a5 = bar; int a6 = 0;
        void* args[] = {&a0,&a1,&a2,&a3,&a4,&a5,&a6};
        hipLaunchCooperativeKernel((void*)lstm_scan_mfma, dim3(NWG), dim3(256), args, 0, stream);
    }
    gemm_logits<<<786, 256, 0, stream>>>(hlast, Wout, bout, out);
}